// Round 9
// baseline (332.971 us; speedup 1.0000x reference)
//
#include <hip/hip_runtime.h>
#include <hip/hip_bf16.h>

// SCM_39676907888322: sigmoid-gated cross attention. fp32 I/O, bf16 MFMA compute.
// R9: back to the verified 3-kernel R7 structure (cooperative launch failed at
//     the API level in R8). attn now processes 64 Q-rows per block (2 q-tiles):
//     every K/V fragment load feeds 2 MFMAs -> K/V cache traffic halves to
//     ~680 MB, still barrier-free in the hot loop. End-of-kernel LDS combine
//     runs once per q-tile.

typedef __bf16 bf16;
typedef __bf16 bf16x8 __attribute__((ext_vector_type(8)));
typedef __bf16 bf16x4 __attribute__((ext_vector_type(4)));
typedef float f32x4 __attribute__((ext_vector_type(4)));
typedef float f32x16 __attribute__((ext_vector_type(16)));

#define NB 8
#define NC 256
#define NCI 128
#define NHW 2304
#define NT32 72    // 2304 / 32

// wpack: [st(6)][ks(8)][ci(128)][c-chunk(32)] bf16  (st = s*3 + {0=v,1=k,2=q})
__global__ __launch_bounds__(256) void wconv_kernel(
    const float* __restrict__ w0, const float* __restrict__ w1,
    const float* __restrict__ w2, const float* __restrict__ w3,
    const float* __restrict__ w4, const float* __restrict__ w5,
    bf16* __restrict__ wp)
{
    int g = blockIdx.x * 256 + threadIdx.x;   // 24576 groups of 8
    int c8 = g & 3;
    int ci = (g >> 2) & 127;
    int stks = g >> 9;                         // 0..47
    int st = stks >> 3, ks = stks & 7;
    const float* w = (st == 0) ? w0 : (st == 1) ? w1 : (st == 2) ? w2
                   : (st == 3) ? w3 : (st == 4) ? w4 : w5;
    const float* src = w + ci * NC + ks * 32 + c8 * 8;
    f32x4 a0 = *(const f32x4*)src;
    f32x4 a1 = *(const f32x4*)(src + 4);
    bf16x8 o;
    #pragma unroll
    for (int j = 0; j < 4; ++j) { o[j] = (bf16)a0[j]; o[4 + j] = (bf16)a1[j]; }
    *(bf16x8*)(wp + (size_t)g * 8) = o;
}

// Qp/Kp: [(s*8+b)][qb/mb(72)][ks(8)][lane(64)][8]  — B/A operand order, k=ci
// Vp:    [(s*8+b)][mb(72)][ks2(2)*4+ct][lane(64)][8] — A operand order, m=c, k=m-dim
__global__ __launch_bounds__(256) void qkv_kernel(
    const float* __restrict__ x1, const float* __restrict__ x2,
    const bf16* __restrict__ wp,
    const float* __restrict__ bv1, const float* __restrict__ bk1, const float* __restrict__ bq1,
    const float* __restrict__ bv2, const float* __restrict__ bk2, const float* __restrict__ bq2,
    bf16* __restrict__ Qp, bf16* __restrict__ Kp, bf16* __restrict__ Vp,
    float* __restrict__ out)
{
    __shared__ __align__(16) bf16 Xt[32 * 264];

    int gid = blockIdx.x;
    int nt = gid % NT32;
    int s = (gid / NT32) & 1;
    int b = gid / (2 * NT32);
    int n0 = nt * 32;

    const float* x = s ? x2 : x1;
    const float* bv = s ? bv2 : bv1;
    const float* bk = s ? bk2 : bk1;
    const float* bq = s ? bq2 : bq1;
    float* outy = out + (size_t)s * (NB * 384 * NHW);

    int tid = threadIdx.x;
    {   // coalesced staging + fp32 concat passthrough
        int noff = (tid & 7) * 4;
        int cbase = tid >> 3;
        #pragma unroll
        for (int i = 0; i < 8; ++i) {
            int c = cbase + i * 32;
            const float* src = x + ((size_t)(b * NC + c) * NHW + n0 + noff);
            f32x4 a = *(const f32x4*)src;
            *(f32x4*)(outy + ((size_t)(b * 384 + c) * NHW + n0 + noff)) = a;
            #pragma unroll
            for (int j = 0; j < 4; ++j)
                Xt[(noff + j) * 264 + c] = (bf16)a[j];
        }
    }
    __syncthreads();

    int lane = tid & 63;
    int wid = tid >> 6;
    int row = lane & 15, quad = lane >> 4;

    f32x4 acc[3][2][2];                  // [t: 0=q,1=k,2=v][mi][jj]
    #pragma unroll
    for (int t = 0; t < 3; ++t)
        #pragma unroll
        for (int mi = 0; mi < 2; ++mi)
            #pragma unroll
            for (int j = 0; j < 2; ++j)
                acc[t][mi][j] = (f32x4){0.f, 0.f, 0.f, 0.f};

    int stmap[3] = {s * 3 + 2, s * 3 + 1, s * 3 + 0};
    #pragma unroll
    for (int ks = 0; ks < 8; ++ks) {
        bf16x8 bfrag[2];
        int c0 = ks * 32 + quad * 8;
        #pragma unroll
        for (int j = 0; j < 2; ++j)
            bfrag[j] = *(const bf16x8*)&Xt[(j * 16 + row) * 264 + c0];
        #pragma unroll
        for (int t = 0; t < 3; ++t) {
            #pragma unroll
            for (int mi = 0; mi < 2; ++mi) {
                const bf16* wa = wp + (((size_t)(stmap[t] * 8 + ks) * 128 + wid * 32 + mi * 16) * 32)
                               + row * 32 + quad * 8;
                bf16x8 afrag = *(const bf16x8*)wa;
                #pragma unroll
                for (int j = 0; j < 2; ++j)
                    acc[t][mi][j] = __builtin_amdgcn_mfma_f32_16x16x32_bf16(
                        afrag, bfrag[j], acc[t][mi][j], 0, 0, 0);
            }
        }
    }

    size_t qkb = ((size_t)(s * NB + b) * 72 + nt) * 4096;
    int eoff = (quad & 1) * 4;
    int loff = 32 * (quad >> 1);
    #pragma unroll
    for (int mi = 0; mi < 2; ++mi) {
        int ci0 = wid * 32 + mi * 16 + quad * 4;
        int ksl = wid * 2 + mi;
        f32x4 bq4 = *(const f32x4*)&bq[ci0];
        f32x4 bk4 = *(const f32x4*)&bk[ci0];
        f32x4 bv4 = *(const f32x4*)&bv[ci0];
        #pragma unroll
        for (int jj = 0; jj < 2; ++jj) {
            int moff = jj * 16 + row;
            size_t qkoff = qkb + (size_t)ksl * 512 + (size_t)(moff + loff) * 8 + eoff;
            bf16x4 pk;
            #pragma unroll
            for (int r = 0; r < 4; ++r) pk[r] = (bf16)(acc[0][mi][jj][r] + bq4[r]);
            *(bf16x4*)&Qp[qkoff] = pk;
            #pragma unroll
            for (int r = 0; r < 4; ++r) pk[r] = (bf16)(acc[1][mi][jj][r] + bk4[r]);
            *(bf16x4*)&Kp[qkoff] = pk;
            size_t vb = qkb + (size_t)(jj * 4 + wid) * 512
                      + (size_t)(mi * 16 + quad * 4) * 8 + (size_t)(32 * 8) * ((row >> 3) & 1)
                      + (row & 7);
            #pragma unroll
            for (int r = 0; r < 4; ++r)
                Vp[vb + r * 8] = (bf16)(acc[2][mi][jj][r] + bv4[r]);
        }
    }
}

__global__ __launch_bounds__(256) void attn_kernel(
    const bf16* __restrict__ Qp, const bf16* __restrict__ Kp, const bf16* __restrict__ Vp,
    float* __restrict__ out)
{
    __shared__ __align__(16) float CB[8192];   // combine buffer, unused in loop

    int gid = blockIdx.x;
    int b = gid & 7;                 // XCD pin
    int r0 = gid >> 3;               // 0..71
    int dir = r0 & 1;
    int q64 = r0 >> 1;               // 0..35 (64-row q-tile)
    int n0 = q64 * 64;

    int tid = threadIdx.x;
    int lane = tid & 63, w = tid >> 6;
    int l32 = lane & 31, h = lane >> 5;
    bool hb = (h != 0);

    const bf16* qb  = Qp + (((size_t)(dir * NB + b) * 72 + q64 * 2) * 4096);
    const bf16* kb0 = Kp + ((size_t)((dir ^ 1) * NB + b) * 72) * 4096;
    const bf16* vb0 = Vp + ((size_t)((dir ^ 1) * NB + b) * 72) * 4096;
    float* outy = out + (size_t)dir * (NB * 384 * NHW) + ((size_t)b * 384 + 256) * NHW;

    // Q B-frags for BOTH 32-row q-tiles, resident (64 VGPR).
    bf16x8 qf[2][8];
    #pragma unroll
    for (int t = 0; t < 2; ++t)
        #pragma unroll
        for (int ks = 0; ks < 8; ++ks)
            qf[t][ks] = *(const bf16x8*)&qb[t * 4096 + ks * 512 + lane * 8];

    f32x16 o[2][4];                  // O^T partials per q-tile
    #pragma unroll
    for (int t = 0; t < 2; ++t)
        #pragma unroll
        for (int ct = 0; ct < 4; ++ct)
            #pragma unroll
            for (int e = 0; e < 16; ++e) o[t][ct][e] = 0.f;

    union U8 { int i[4]; bf16x8 v; };

    int mb0 = w * 18;                // wave-private 18 m-blocks of 32
    for (int mb = mb0; mb < mb0 + 18; ++mb) {
        const bf16* kb = kb0 + (size_t)mb * 4096;
        const bf16* vb = vb0 + (size_t)mb * 4096;
        // S^T = K Q^T for both q-tiles: each kf feeds 2 MFMAs.
        f32x16 sacc[2];
        #pragma unroll
        for (int t = 0; t < 2; ++t)
            #pragma unroll
            for (int e = 0; e < 16; ++e) sacc[t][e] = 0.f;
        #pragma unroll
        for (int ks = 0; ks < 8; ++ks) {
            bf16x8 kf = *(const bf16x8*)&kb[ks * 512 + lane * 8];
            sacc[0] = __builtin_amdgcn_mfma_f32_32x32x16_bf16(kf, qf[0][ks], sacc[0], 0, 0, 0);
            sacc[1] = __builtin_amdgcn_mfma_f32_32x32x16_bf16(kf, qf[1][ks], sacc[1], 0, 0, 0);
        }
        // sigmoid -> bf16 quads, per q-tile
        int2 pqi[2][4];
        #pragma unroll
        for (int t = 0; t < 2; ++t) {
            #pragma unroll
            for (int g = 0; g < 4; ++g) {
                bf16x4 pq;
                #pragma unroll
                for (int e = 0; e < 4; ++e) {
                    float xv = sacc[t][g * 4 + e];
                    float ex = __expf(-xv);
                    pq[e] = (bf16)__builtin_amdgcn_rcpf(1.0f + ex);
                }
                pqi[t][g] = *(int2*)&pq;
            }
        }
        // PV: each vf feeds 2 MFMAs.
        #pragma unroll
        for (int ks2 = 0; ks2 < 2; ++ks2) {
            U8 u[2];
            #pragma unroll
            for (int t = 0; t < 2; ++t) {
                int2 own  = hb ? pqi[t][2 * ks2 + 1] : pqi[t][2 * ks2];
                int2 send = hb ? pqi[t][2 * ks2]     : pqi[t][2 * ks2 + 1];
                int2 recv;
                recv.x = __shfl_xor(send.x, 32, 64);
                recv.y = __shfl_xor(send.y, 32, 64);
                int2 lo = hb ? recv : own;
                int2 hi = hb ? own : recv;
                u[t].i[0] = lo.x; u[t].i[1] = lo.y; u[t].i[2] = hi.x; u[t].i[3] = hi.y;
            }
            const bf16* vbs = vb + ks2 * 2048;
            #pragma unroll
            for (int ct = 0; ct < 4; ++ct) {
                bf16x8 vf = *(const bf16x8*)&vbs[ct * 512 + lane * 8];
                o[0][ct] = __builtin_amdgcn_mfma_f32_32x32x16_bf16(vf, u[0].v, o[0][ct], 0, 0, 0);
                o[1][ct] = __builtin_amdgcn_mfma_f32_32x32x16_bf16(vf, u[1].v, o[1][ct], 0, 0, 0);
            }
        }
    }

    // ---- Combine 4 waves' partials via LDS, once per q-tile ----
    for (int t = 0; t < 2; ++t) {
        int nq = n0 + t * 32;
        __syncthreads();
        if (w >= 2) {
            float* dst = CB + (w - 2) * 4096;
            #pragma unroll
            for (int ct = 0; ct < 4; ++ct)
                #pragma unroll
                for (int g = 0; g < 4; ++g) {
                    f32x4 pk;
                    #pragma unroll
                    for (int e = 0; e < 4; ++e) pk[e] = o[t][ct][g * 4 + e];
                    *(f32x4*)&dst[(ct * 4 + g) * 256 + lane * 4] = pk;
                }
        }
        __syncthreads();
        if (w < 2) {
            const float* src = CB + w * 4096;
            #pragma unroll
            for (int ct = 0; ct < 4; ++ct)
                #pragma unroll
                for (int g = 0; g < 4; ++g) {
                    f32x4 pk = *(const f32x4*)&src[(ct * 4 + g) * 256 + lane * 4];
                    #pragma unroll
                    for (int e = 0; e < 4; ++e) o[t][ct][g * 4 + e] += pk[e];
                }
        }
        __syncthreads();
        if (w == 0) {                // cross-swap: w0 -> finalizes ct{0,1}
            #pragma unroll
            for (int ct = 2; ct < 4; ++ct)
                #pragma unroll
                for (int g = 0; g < 4; ++g) {
                    f32x4 pk;
                    #pragma unroll
                    for (int e = 0; e < 4; ++e) pk[e] = o[t][ct][g * 4 + e];
                    *(f32x4*)&CB[((ct - 2) * 4 + g) * 256 + lane * 4] = pk;
                }
        } else if (w == 1) {
            #pragma unroll
            for (int ct = 0; ct < 2; ++ct)
                #pragma unroll
                for (int g = 0; g < 4; ++g) {
                    f32x4 pk;
                    #pragma unroll
                    for (int e = 0; e < 4; ++e) pk[e] = o[t][ct][g * 4 + e];
                    *(f32x4*)&CB[2048 + (ct * 4 + g) * 256 + lane * 4] = pk;
                }
        }
        __syncthreads();
        if (w == 0) {
            #pragma unroll
            for (int ct = 0; ct < 2; ++ct)
                #pragma unroll
                for (int g = 0; g < 4; ++g) {
                    f32x4 pk = *(const f32x4*)&CB[2048 + (ct * 4 + g) * 256 + lane * 4];
                    #pragma unroll
                    for (int e = 0; e < 4; ++e) {
                        int c = ct * 32 + e + 8 * g + 4 * h;
                        outy[(size_t)c * NHW + nq + l32] = pk[e] + o[t][ct][g * 4 + e];
                    }
                }
        } else if (w == 1) {
            #pragma unroll
            for (int ct = 2; ct < 4; ++ct)
                #pragma unroll
                for (int g = 0; g < 4; ++g) {
                    f32x4 pk = *(const f32x4*)&CB[((ct - 2) * 4 + g) * 256 + lane * 4];
                    #pragma unroll
                    for (int e = 0; e < 4; ++e) {
                        int c = ct * 32 + e + 8 * g + 4 * h;
                        outy[(size_t)c * NHW + nq + l32] = pk[e] + o[t][ct][g * 4 + e];
                    }
                }
        }
    }
}

extern "C" void kernel_launch(void* const* d_in, const int* in_sizes, int n_in,
                              void* d_out, int out_size, void* d_ws, size_t ws_size,
                              hipStream_t stream) {
    const float* x1  = (const float*)d_in[0];
    const float* x2  = (const float*)d_in[1];
    const float* wv1 = (const float*)d_in[2];  const float* bv1 = (const float*)d_in[3];
    const float* wk1 = (const float*)d_in[4];  const float* bk1 = (const float*)d_in[5];
    const float* wq1 = (const float*)d_in[6];  const float* bq1 = (const float*)d_in[7];
    const float* wv2 = (const float*)d_in[8];  const float* bv2 = (const float*)d_in[9];
    const float* wk2 = (const float*)d_in[10]; const float* bk2 = (const float*)d_in[11];
    const float* wq2 = (const float*)d_in[12]; const float* bq2 = (const float*)d_in[13];
    float* out = (float*)d_out;

    // ws (bf16): Qp | Kp | Vp (each 2*8*72*4096 = 4718592 elems) | wpack (196608)
    size_t per = (size_t)2 * NB * 72 * 4096;
    bf16* Qp = (bf16*)d_ws;
    bf16* Kp = Qp + per;
    bf16* Vp = Kp + per;
    bf16* wp = Vp + per;

    wconv_kernel<<<dim3(96), dim3(256), 0, stream>>>(wv1, wk1, wq1, wv2, wk2, wq2, wp);

    qkv_kernel<<<dim3(NB * 2 * NT32), dim3(256), 0, stream>>>(
        x1, x2, wp, bv1, bk1, bq1, bv2, bk2, bq2, Qp, Kp, Vp, out);

    attn_kernel<<<dim3(NB * 2 * 36), dim3(256), 0, stream>>>(Qp, Kp, Vp, out);
}